// Round 1
// baseline (346.649 us; speedup 1.0000x reference)
//
#include <hip/hip_runtime.h>
#include <stdint.h>

#define GS   512   // graph size N
#define CF   128   // C_IN = C_OUT
#define XROW 640   // GS + CF
#define NB   128   // batch

typedef __attribute__((ext_vector_type(4))) float          f32x4;
typedef __attribute__((ext_vector_type(8))) short          s16x8;
typedef __attribute__((ext_vector_type(4))) unsigned short u16x4;

__device__ __forceinline__ unsigned short f2bf(float f) {
    unsigned u = __builtin_bit_cast(unsigned, f);
    u = (u + 0x7fffu + ((u >> 16) & 1u)) >> 16;   // RNE
    return (unsigned short)u;
}
__device__ __forceinline__ float bf2f(unsigned short h) {
    unsigned u = ((unsigned)h) << 16;
    return __builtin_bit_cast(float, u);
}
__device__ __forceinline__ void glds16(const void* g, void* l) {
    __builtin_amdgcn_global_load_lds(
        (const __attribute__((address_space(1))) void*)g,
        (__attribute__((address_space(3))) void*)l, 16, 0, 0);
}

// ---------------------------------------------------------------------------
// k1: per-row degree -> dis = rsqrt(deg); also copy A (fp32) to out[:, :, 0:512]
// one wave per row (512 floats = 64 lanes x 2 float4)
// ---------------------------------------------------------------------------
__global__ __launch_bounds__(256) void k1_deg_copy(const float* __restrict__ X,
                                                   float* __restrict__ out,
                                                   float* __restrict__ dis) {
    const int wv = threadIdx.x >> 6, l = threadIdx.x & 63;
    const int gr = (blockIdx.x << 2) + wv;               // global row, [0, NB*GS)
    const f32x4* rp = (const f32x4*)(X + (size_t)gr * XROW);
    f32x4* op = (f32x4*)(out + (size_t)gr * XROW);
    f32x4 v0 = rp[l], v1 = rp[l + 64];
    op[l] = v0; op[l + 64] = v1;
    float s = (v0[0] + v0[1]) + (v0[2] + v0[3]) + (v1[0] + v1[1]) + (v1[2] + v1[3]);
#pragma unroll
    for (int off = 32; off; off >>= 1) s += __shfl_xor(s, off, 64);
    if (l == 0) dis[gr] = (s > 0.f) ? (1.f / sqrtf(s)) : 0.f;
}

// ---------------------------------------------------------------------------
// k2: featWD_T[b][f][m] = bf16( dis[b,m] * (feat[b,m,:] @ W)[f] )
// block = 64 rows, full K=128. feat tile staged via global_load_lds with
// 16B-chunk XOR swizzle; W^T in padded LDS.
// ---------------------------------------------------------------------------
__global__ __launch_bounds__(256) void k2_featw(const float* __restrict__ X,
                                                const float* __restrict__ W,
                                                const float* __restrict__ dis,
                                                unsigned short* __restrict__ fwdT) {
    __shared__ __align__(16) float sf[64 * 128];            // feat tile (swizzled)
    __shared__ __align__(16) unsigned short swt[128 * 136]; // W^T, +8 pad
    const int t = threadIdx.x, l = t & 63, wv = t >> 6;
    const int m0 = blockIdx.x << 6;          // global row base
    const int b  = m0 >> 9;
    const int ml0 = m0 & (GS - 1);

    // stage feat tile: 64 rows x 128 fp32 (512B/row = 32 x 16B chunks)
    const char* fb = (const char*)(X + (size_t)m0 * XROW + GS);
    char* sfb = (char*)sf;
#pragma unroll
    for (int it = 0; it < 8; ++it) {
        int chunk = it * 256 + t;
        int row = chunk >> 5, c16 = chunk & 31;
        int c16s = c16 ^ (row & 7);                          // pre-swizzled source
        glds16(fb + (size_t)row * (XROW * 4) + c16s * 16,
               sfb + it * 4096 + wv * 1024);
    }
    // stage W^T as bf16 (transpose in-kernel, once per block)
    {
        int c = t >> 1, f0 = (t & 1) << 6;
        const float* wp = W + c * CF + f0;
#pragma unroll 8
        for (int j = 0; j < 64; ++j)
            swt[(f0 + j) * 136 + c] = f2bf(wp[j]);
    }
    __syncthreads();

    const int wr = wv >> 1, wc = wv & 1;
    const int lr = l & 15, lk = l >> 4;
    f32x4 acc[2][4];
#pragma unroll
    for (int i = 0; i < 2; ++i)
#pragma unroll
        for (int j = 0; j < 4; ++j)
#pragma unroll
            for (int r = 0; r < 4; ++r) acc[i][j][r] = 0.f;

#pragma unroll
    for (int ks = 0; ks < 4; ++ks) {
        s16x8 af[2];
#pragma unroll
        for (int i = 0; i < 2; ++i) {
            int row = (wr << 5) + (i << 4) + lr;
            int cb = (ks << 3) + (lk << 1);
            int c0 = cb ^ (row & 7), c1 = (cb + 1) ^ (row & 7);
            f32x4 x0 = *(const f32x4*)&sf[row * 128 + (c0 << 2)];
            f32x4 x1 = *(const f32x4*)&sf[row * 128 + (c1 << 2)];
            s16x8 a;
            a[0] = f2bf(x0[0]); a[1] = f2bf(x0[1]); a[2] = f2bf(x0[2]); a[3] = f2bf(x0[3]);
            a[4] = f2bf(x1[0]); a[5] = f2bf(x1[1]); a[6] = f2bf(x1[2]); a[7] = f2bf(x1[3]);
            af[i] = a;
        }
#pragma unroll
        for (int j = 0; j < 4; ++j) {
            int f = (wc << 6) + (j << 4) + lr;
            s16x8 bf = *(const s16x8*)&swt[f * 136 + (ks << 5) + (lk << 3)];
#pragma unroll
            for (int i = 0; i < 2; ++i)
                acc[i][j] = __builtin_amdgcn_mfma_f32_16x16x32_bf16(af[i], bf, acc[i][j], 0, 0, 0);
        }
    }

    // epilogue: scale by dis[m], store transposed bf16 [b][f][m]
#pragma unroll
    for (int i = 0; i < 2; ++i) {
        int mr = (wr << 5) + (i << 4) + (lk << 2);
        f32x4 d4 = *(const f32x4*)&dis[m0 + mr];
#pragma unroll
        for (int j = 0; j < 4; ++j) {
            int f = (wc << 6) + (j << 4) + lr;
            u16x4 o;
            o[0] = f2bf(d4[0] * acc[i][j][0]);
            o[1] = f2bf(d4[1] * acc[i][j][1]);
            o[2] = f2bf(d4[2] * acc[i][j][2]);
            o[3] = f2bf(d4[3] * acc[i][j][3]);
            *(u16x4*)&fwdT[((size_t)(b * CF + f) << 9) + ml0 + mr] = o;
        }
    }
}

// ---------------------------------------------------------------------------
// k3: out[b,n,512+f] = relu( dis[n] * (A[n,:] @ featWD[:,f] + featWD[n,f]) )
// 64x128 tile per block, BK=32, double-buffered global_load_lds staging.
// A tile fp32 swizzled; B tile = featWD_T rows (16B-contiguous fragments).
// ---------------------------------------------------------------------------
__global__ __launch_bounds__(256) void k3_gcn(const float* __restrict__ X,
                                              const float* __restrict__ dis,
                                              const unsigned short* __restrict__ fwdT,
                                              float* __restrict__ out) {
    __shared__ __align__(16) float sa[2][64 * 32];            // 8KB each
    __shared__ __align__(16) unsigned short sb[2][128 * 32];  // 8KB each
    const int t = threadIdx.x, l = t & 63, wv = t >> 6;
    const int b = blockIdx.x >> 3;
    const int bm0 = (blockIdx.x & 7) << 6;                    // row base in batch
    const char* Ab = (const char*)(X + ((size_t)b * GS + bm0) * XROW);
    const unsigned short* Bb = fwdT + ((size_t)(b * CF) << 9);

    const int wr = wv >> 1, wc = wv & 1;
    const int lr = l & 15, lk = l >> 4;

    auto stage = [&](int buf, int kt) {
#pragma unroll
        for (int it = 0; it < 2; ++it) {                       // A: 64 rows x 8 chunks
            int chunk = it * 256 + t;
            int row = chunk >> 3, c16 = chunk & 7;
            int c16s = c16 ^ (row & 7);
            glds16(Ab + (size_t)row * (XROW * 4) + kt * 128 + c16s * 16,
                   (char*)sa[buf] + it * 4096 + wv * 1024);
        }
#pragma unroll
        for (int it = 0; it < 2; ++it) {                       // B: 128 f x 4 chunks
            int chunk = it * 256 + t;
            int f = chunk >> 2, c16 = chunk & 3;
            glds16((const char*)Bb + ((size_t)f << 10) + kt * 64 + c16 * 16,
                   (char*)sb[buf] + it * 4096 + wv * 1024);
        }
    };

    f32x4 acc[2][4];
#pragma unroll
    for (int i = 0; i < 2; ++i)
#pragma unroll
        for (int j = 0; j < 4; ++j)
#pragma unroll
            for (int r = 0; r < 4; ++r) acc[i][j][r] = 0.f;

    stage(0, 0);
    int cur = 0;
    for (int kt = 0; kt < 16; ++kt) {
        __syncthreads();                                      // drains staging vmcnt
        if (kt < 15) stage(cur ^ 1, kt + 1);                  // prefetch next tile
        s16x8 af[2];
#pragma unroll
        for (int i = 0; i < 2; ++i) {
            int row = (wr << 5) + (i << 4) + lr;
            int cb = lk << 1;
            int c0 = cb ^ (row & 7), c1 = (cb + 1) ^ (row & 7);
            const float* rbase = &sa[cur][row << 5];
            f32x4 x0 = *(const f32x4*)(rbase + (c0 << 2));
            f32x4 x1 = *(const f32x4*)(rbase + (c1 << 2));
            s16x8 a;
            a[0] = f2bf(x0[0]); a[1] = f2bf(x0[1]); a[2] = f2bf(x0[2]); a[3] = f2bf(x0[3]);
            a[4] = f2bf(x1[0]); a[5] = f2bf(x1[1]); a[6] = f2bf(x1[2]); a[7] = f2bf(x1[3]);
            af[i] = a;
        }
#pragma unroll
        for (int j = 0; j < 4; ++j) {
            int f = (wc << 6) + (j << 4) + lr;
            s16x8 bf = *(const s16x8*)&sb[cur][(f << 5) + (lk << 3)];
#pragma unroll
            for (int i = 0; i < 2; ++i)
                acc[i][j] = __builtin_amdgcn_mfma_f32_16x16x32_bf16(af[i], bf, acc[i][j], 0, 0, 0);
        }
        cur ^= 1;
    }

    // epilogue: + identity featWD[n,f], * dis[n], relu, store fp32
#pragma unroll
    for (int i = 0; i < 2; ++i) {
        int nr = bm0 + (wr << 5) + (i << 4) + (lk << 2);      // batch-local n (base of 4)
        f32x4 d4 = *(const f32x4*)&dis[(b << 9) + nr];
#pragma unroll
        for (int j = 0; j < 4; ++j) {
            int f = (wc << 6) + (j << 4) + lr;
            u16x4 fw = *(const u16x4*)&Bb[((size_t)f << 9) + nr];
#pragma unroll
            for (int r = 0; r < 4; ++r) {
                float v = d4[r] * (acc[i][j][r] + bf2f(fw[r]));
                out[(size_t)(b * GS + nr + r) * XROW + GS + f] = v > 0.f ? v : 0.f;
            }
        }
    }
}

extern "C" void kernel_launch(void* const* d_in, const int* in_sizes, int n_in,
                              void* d_out, int out_size, void* d_ws, size_t ws_size,
                              hipStream_t stream) {
    const float* X = (const float*)d_in[0];
    const float* W = (const float*)d_in[1];
    float* out = (float*)d_out;
    float* dis = (float*)d_ws;                                       // NB*GS fp32 = 256KB
    unsigned short* fwdT = (unsigned short*)((char*)d_ws + (size_t)NB * GS * 4); // 16.8MB bf16

    hipLaunchKernelGGL(k1_deg_copy, dim3(NB * GS / 4),  dim3(256), 0, stream, X, out, dis);
    hipLaunchKernelGGL(k2_featw,    dim3(NB * GS / 64), dim3(256), 0, stream, X, W, dis, fwdT);
    hipLaunchKernelGGL(k3_gcn,      dim3(NB * GS / 64), dim3(256), 0, stream, X, dis, fwdT, out);
}